// Round 5
// baseline (362.993 us; speedup 1.0000x reference)
//
#include <hip/hip_runtime.h>
#include <hip/hip_cooperative_groups.h>

namespace cg = cooperative_groups;

#define H_ 4
#define N_ 1024
#define E_ 4096
#define LE_ 16384
#define FN_ 128
#define FE_ 64
#define HTN_ 16384   // node-pair hash slots (4x E)
#define HTE_ 65536   // line-pair hash slots (4x LE)

struct P {
  const float *Xn, *Xe;
  const int *src, *dst, *lgs, *lgd;
  const float *nqW, *nqb, *nkW, *nkb, *nvW, *nvb;
  const float *eqW, *eqb, *ekW, *ekb, *evW, *evb;
  const float *ncW, *ncb, *ecW, *ecb;
  float *out;
  float *NV, *EV, *NK, *EK, *nsa, *esa, *nagg, *eagg;
  int *hkN, *hvN, *hkE, *hvE;
};

__device__ __forceinline__ unsigned hashN(int key) {
  return (((unsigned)key * 2654435761u) >> 16) & (HTN_ - 1);
}
__device__ __forceinline__ unsigned hashE(int key) {
  return (((unsigned)key * 2654435761u) >> 16) & (HTE_ - 1);
}

// ---------------------------------------------------------------------------
// One 64x64 GEMM tile: C[r0..+64, o0..+64] = [relu](X @ W^T + b).
// XOR-swizzled k-major LDS (verified R2/R3). 256 threads.
// ---------------------------------------------------------------------------
template<int K, bool RELU>
__device__ void gemm_tile(const float* __restrict__ X, const float* __restrict__ W,
                          const float* __restrict__ b, float* __restrict__ C,
                          int O, int r0, int o0, float* smem, int t) {
  float* Xs = smem;
  float* Ws = smem + 2048;
  const int tn = t & 15, tm = t >> 4;
  float acc[4][4] = {};
  for (int k0 = 0; k0 < K; k0 += 32) {
#pragma unroll
    for (int ph = 0; ph < 2; ++ph) {
      int i4 = t + ph * 256;
      int m = i4 >> 3;
      int k4 = (i4 & 7) << 2;
      int m4 = m >> 2, ml = m & 3;
      float4 vx = *(const float4*)&X[(r0 + m) * K + k0 + k4];
      float4 vw = *(const float4*)&W[(o0 + m) * K + k0 + k4];
      Xs[(k4 + 0) * 64 + ((m4 ^ ((k4 + 0) & 15)) << 2) + ml] = vx.x;
      Xs[(k4 + 1) * 64 + ((m4 ^ ((k4 + 1) & 15)) << 2) + ml] = vx.y;
      Xs[(k4 + 2) * 64 + ((m4 ^ ((k4 + 2) & 15)) << 2) + ml] = vx.z;
      Xs[(k4 + 3) * 64 + ((m4 ^ ((k4 + 3) & 15)) << 2) + ml] = vx.w;
      Ws[(k4 + 0) * 64 + ((m4 ^ ((k4 + 0) & 15)) << 2) + ml] = vw.x;
      Ws[(k4 + 1) * 64 + ((m4 ^ ((k4 + 1) & 15)) << 2) + ml] = vw.y;
      Ws[(k4 + 2) * 64 + ((m4 ^ ((k4 + 2) & 15)) << 2) + ml] = vw.z;
      Ws[(k4 + 3) * 64 + ((m4 ^ ((k4 + 3) & 15)) << 2) + ml] = vw.w;
    }
    __syncthreads();
#pragma unroll
    for (int k = 0; k < 32; ++k) {
      float4 a = *(const float4*)&Xs[k * 64 + ((tm ^ (k & 15)) << 2)];
      float4 b4 = *(const float4*)&Ws[k * 64 + ((tn ^ (k & 15)) << 2)];
      acc[0][0] += a.x * b4.x; acc[0][1] += a.x * b4.y; acc[0][2] += a.x * b4.z; acc[0][3] += a.x * b4.w;
      acc[1][0] += a.y * b4.x; acc[1][1] += a.y * b4.y; acc[1][2] += a.y * b4.z; acc[1][3] += a.y * b4.w;
      acc[2][0] += a.z * b4.x; acc[2][1] += a.z * b4.y; acc[2][2] += a.z * b4.z; acc[2][3] += a.z * b4.w;
      acc[3][0] += a.w * b4.x; acc[3][1] += a.w * b4.y; acc[3][2] += a.w * b4.z; acc[3][3] += a.w * b4.w;
    }
    __syncthreads();
  }
  float4 bv = *(const float4*)&b[o0 + tn * 4];
#pragma unroll
  for (int i = 0; i < 4; ++i) {
    float4 o;
    o.x = acc[i][0] + bv.x; o.y = acc[i][1] + bv.y;
    o.z = acc[i][2] + bv.z; o.w = acc[i][3] + bv.w;
    if (RELU) {
      o.x = fmaxf(o.x, 0.f); o.y = fmaxf(o.y, 0.f);
      o.z = fmaxf(o.z, 0.f); o.w = fmaxf(o.w, 0.f);
    }
    *(float4*)&C[(r0 + tm * 4 + i) * O + o0 + tn * 4] = o;
  }
}

// ---------------------------------------------------------------------------
// Shared init/proj/insert/scatter bodies (used by both coop and fallback paths)
// ---------------------------------------------------------------------------
__device__ void zero_and_init(const P& p, int lane, int nlanes) {
  float4 z4 = make_float4(0.f, 0.f, 0.f, 0.f);
  float4* zb = (float4*)p.nagg;          // nagg+eagg contiguous: 1572864 floats
  for (int i = lane; i < 1572864 / 4; i += nlanes) zb[i] = z4;
  int4 m4 = make_int4(-1, -1, -1, -1);
  int4* hb = (int4*)p.hkN;               // hkN,hvN,hkE,hvE contiguous: 163840 ints
  for (int i = lane; i < 163840 / 4; i += nlanes) hb[i] = m4;
}

__device__ void kproj_item(const P& p, int idx) {   // idx in [0, N*H + E*H)
  if (idx < N_ * H_) {
    int r = idx >> 2, o = idx & 3;
    const float4* x4 = (const float4*)(p.Xn + r * FN_);
    const float4* w4 = (const float4*)(p.nkW + o * FN_);
    float acc = p.nkb[o];
    for (int k = 0; k < 32; ++k) {
      float4 x = x4[k], w = w4[k];
      acc += x.x * w.x + x.y * w.y + x.z * w.z + x.w * w.w;
    }
    p.NK[idx] = acc;
  } else {
    int j = idx - N_ * H_;
    int r = j >> 2, o = j & 3;
    const float4* x4 = (const float4*)(p.Xe + r * FE_);
    const float4* w4 = (const float4*)(p.ekW + o * FE_);
    float acc = p.ekb[o];
    for (int k = 0; k < 16; ++k) {
      float4 x = x4[k], w = w4[k];
      acc += x.x * w.x + x.y * w.y + x.z * w.z + x.w * w.w;
    }
    p.EK[j] = acc;
  }
}

__device__ void insert_item(const P& p, int idx) {  // idx in [0, E + LE)
  if (idx < E_) {
    int key = p.src[idx] * N_ + p.dst[idx];
    unsigned slot = hashN(key);
    while (true) {
      int prev = atomicCAS(&p.hkN[slot], -1, key);
      if (prev == -1 || prev == key) break;
      slot = (slot + 1) & (HTN_ - 1);
    }
    atomicMax(&p.hvN[slot], idx);
  } else {
    int l = idx - E_;
    int key = p.lgs[l] * E_ + p.lgd[l];
    unsigned slot = hashE(key);
    while (true) {
      int prev = atomicCAS(&p.hkE[slot], -1, key);
      if (prev == -1 || prev == key) break;
      slot = (slot + 1) & (HTE_ - 1);
    }
    atomicMax(&p.hvE[slot], l);
  }
}

__device__ void scatter_node_item(const P& p, int idx) {  // idx in [0, E*32)
  int e = idx >> 5, f4 = idx & 31;
  int s = p.src[e], d = p.dst[e];
  int key = s * N_ + d;
  unsigned slot = hashN(key);
  while (p.hkN[slot] != key) slot = (slot + 1) & (HTN_ - 1);
  if (p.hvN[slot] != e) return;
#pragma unroll
  for (int h = 0; h < H_; ++h) {
    float a = p.esa[h * E_ + e];
    float4 v = ((const float4*)(p.NV + h * (N_ * FN_) + d * FN_))[f4];
    float* dp = p.nagg + h * (N_ * FN_) + s * FN_ + f4 * 4;
    atomicAdd(dp + 0, a * v.x); atomicAdd(dp + 1, a * v.y);
    atomicAdd(dp + 2, a * v.z); atomicAdd(dp + 3, a * v.w);
  }
}

__device__ void scatter_edge_item(const P& p, int idx) {  // idx in [0, LE*16)
  int l = idx >> 4, f4 = idx & 15;
  int j = p.lgs[l], c = p.lgd[l];
  int key = j * E_ + c;
  unsigned slot = hashE(key);
  while (p.hkE[slot] != key) slot = (slot + 1) & (HTE_ - 1);
  if (p.hvE[slot] != l) return;
  int cn = p.dst[j];
#pragma unroll
  for (int h = 0; h < H_; ++h) {
    float a = p.nsa[h * N_ + cn];
    float4 v = ((const float4*)(p.EV + h * (E_ * FE_) + c * FE_))[f4];
    float* dp = p.eagg + h * (E_ * FE_) + j * FE_ + f4 * 4;
    atomicAdd(dp + 0, a * v.x); atomicAdd(dp + 1, a * v.y);
    atomicAdd(dp + 2, a * v.z); atomicAdd(dp + 3, a * v.w);
  }
}

// LDS layout for attention (offsets in floats, 16B-aligned)
#define LA_YS  0      // 512
#define LA_TS  512    // 128
#define LA_ZS  640    // 4*132
#define LA_DS  1168   // 4
#define LA_SIG 1172   // 4
#define LA_RED 1176   // 256
#define LA_SC  1432   // 4096
#define SMEM_F 5528

// ---------------------------------------------------------------------------
// Node head attention (R3-verified formulas), 256 threads.
// position i = 4j + c <-> lin row r = h*256 + j, weight slice c.
// ---------------------------------------------------------------------------
__device__ void attn_node(const P& p, int h, int t, float* smem) {
  float* ys = smem + LA_YS; float* ts = smem + LA_TS; float* zs = smem + LA_ZS;
  float* ds = smem + LA_DS; float* sig = smem + LA_SIG;
  float* red = smem + LA_RED; float* sc = smem + LA_SC;
  const int r0 = h * 256;
  const float4* NK4 = (const float4*)p.NK;
  {  // y partials: g = t&127, half = t>>7 over 128 rows each
    int g = t & 127, half = t >> 7;
    float a0 = 0, a1 = 0, a2 = 0, a3 = 0;
    for (int jj = 0; jj < 128; ++jj) {
      int r = r0 + half * 128 + jj;
      float x = p.Xn[r * FN_ + g];
      float4 k = NK4[r];
      a0 += x * k.x; a1 += x * k.y; a2 += x * k.z; a3 += x * k.w;
    }
    ((float4*)sc)[t] = make_float4(a0, a1, a2, a3);
  }
  __syncthreads();
  if (t < 128) {
    float4 a = ((float4*)sc)[t], b = ((float4*)sc)[128 + t];
    ((float4*)ys)[t] = make_float4(a.x + b.x, a.y + b.y, a.z + b.z, a.w + b.w);
  } else if (t < 160) {
    int t2 = t - 128, c = t2 & 3, part = t2 >> 2;
    float s = 0.f;
    for (int j = 0; j < 32; ++j) s += p.NK[(r0 + part * 32 + j) * 4 + c];
    red[t2] = s;
  }
  __syncthreads();
  if (t < 4) { float s = 0.f; for (int q = 0; q < 8; ++q) s += red[q * 4 + t]; sig[t] = s; }
  __syncthreads();
  {  // t[f] partials: thread (f = t&127, cp = t>>7) covers c = 2cp, 2cp+1
    int f = t & 127, cp = t >> 7;
    float s = 0.f;
    for (int ci = 0; ci < 2; ++ci) {
      int c = cp * 2 + ci;
      const float4* w4 = (const float4*)(p.nqW + (c * 128 + f) * 128);
      float acc = 0.f;
      for (int g4 = 0; g4 < 32; ++g4) {
        float4 w = w4[g4];
        acc += w.x * ys[(g4 * 4 + 0) * 4 + c] + w.y * ys[(g4 * 4 + 1) * 4 + c]
             + w.z * ys[(g4 * 4 + 2) * 4 + c] + w.w * ys[(g4 * 4 + 3) * 4 + c];
      }
      s += acc;
    }
    red[t] = s;
  }
  __syncthreads();
  if (t < 128) {
    float s = red[t] + red[128 + t];
    float bb = 0.f;
    for (int c = 0; c < 4; ++c) bb += p.nqb[c * 128 + t] * sig[c];
    ts[t] = s + bb;
  }
  __syncthreads();
  for (int rep = 0; rep < 2; ++rep) {  // z: 512 outputs
    int idx = rep * 256 + t;
    int c = idx >> 7, g = idx & 127;
    float s = 0.f;
    for (int f = 0; f < 128; ++f) s += p.nqW[(c * 128 + f) * 128 + g] * ts[f];
    zs[c * 132 + g] = s;
  }
  if (t < 4) {
    float s = 0.f;
    for (int f = 0; f < 128; ++f) s += p.nqb[t * 128 + f] * ts[f];
    ds[t] = s;
  }
  __syncthreads();
  float s4[4];
  {  // scores: row j = t -> positions 4t..4t+3
    const float4* x4 = (const float4*)(p.Xn + (r0 + t) * FN_);
    s4[0] = ds[0]; s4[1] = ds[1]; s4[2] = ds[2]; s4[3] = ds[3];
    for (int g4 = 0; g4 < 32; ++g4) {
      float4 x = x4[g4];
#pragma unroll
      for (int c = 0; c < 4; ++c) {
        const float* z = zs + c * 132 + g4 * 4;
        s4[c] += x.x * z[0] + x.y * z[1] + x.z * z[2] + x.w * z[3];
      }
    }
  }
  red[t] = fmaxf(fmaxf(s4[0], s4[1]), fmaxf(s4[2], s4[3]));
  __syncthreads();
  for (int off = 128; off > 0; off >>= 1) {
    if (t < off) red[t] = fmaxf(red[t], red[t + off]);
    __syncthreads();
  }
  float m = red[0];
  __syncthreads();
  float e0 = expf(s4[0] - m), e1 = expf(s4[1] - m), e2 = expf(s4[2] - m), e3 = expf(s4[3] - m);
  red[t] = e0 + e1 + e2 + e3;
  __syncthreads();
  for (int off = 128; off > 0; off >>= 1) {
    if (t < off) red[t] += red[t + off];
    __syncthreads();
  }
  float inv = 1.f / red[0];
  ((float4*)(p.nsa + h * N_))[t] = make_float4(e0 * inv, e1 * inv, e2 * inv, e3 * inv);
}

// ---------------------------------------------------------------------------
// Edge head attention: 256 threads; 1024 lin rows, 4096 positions.
// ---------------------------------------------------------------------------
__device__ void attn_edge(const P& p, int h, int t, float* smem) {
  float* ys = smem + LA_YS; float* ts = smem + LA_TS; float* zs = smem + LA_ZS;
  float* ds = smem + LA_DS; float* sig = smem + LA_SIG;
  float* red = smem + LA_RED; float* sc = smem + LA_SC;
  const int r0 = h * 1024;
  const float4* EK4 = (const float4*)p.EK;
  {  // y partials: g = t&63, q = t>>6 over 256 rows each
    int g = t & 63, q = t >> 6;
    float a0 = 0, a1 = 0, a2 = 0, a3 = 0;
    for (int jj = 0; jj < 256; ++jj) {
      int r = r0 + q * 256 + jj;
      float x = p.Xe[r * FE_ + g];
      float4 k = EK4[r];
      a0 += x * k.x; a1 += x * k.y; a2 += x * k.z; a3 += x * k.w;
    }
    ((float4*)sc)[t] = make_float4(a0, a1, a2, a3);
  }
  __syncthreads();
  if (t < 64) {
    float4 a = ((float4*)sc)[t], b = ((float4*)sc)[64 + t];
    float4 c4 = ((float4*)sc)[128 + t], d4 = ((float4*)sc)[192 + t];
    ((float4*)ys)[t] = make_float4(a.x + b.x + c4.x + d4.x, a.y + b.y + c4.y + d4.y,
                                   a.z + b.z + c4.z + d4.z, a.w + b.w + c4.w + d4.w);
  } else if (t < 96) {
    int t2 = t - 64, c = t2 & 3, part = t2 >> 2;
    float s = 0.f;
    for (int j = 0; j < 128; ++j) s += p.EK[(r0 + part * 128 + j) * 4 + c];
    red[t2] = s;
  }
  __syncthreads();
  if (t < 4) { float s = 0.f; for (int q = 0; q < 8; ++q) s += red[q * 4 + t]; sig[t] = s; }
  __syncthreads();
  {  // t[f] partials: thread (c = t>>6, f = t&63)
    int c = t >> 6, f = t & 63;
    const float4* w4 = (const float4*)(p.eqW + (c * 64 + f) * 64);
    float acc = 0.f;
    for (int g4 = 0; g4 < 16; ++g4) {
      float4 w = w4[g4];
      acc += w.x * ys[(g4 * 4 + 0) * 4 + c] + w.y * ys[(g4 * 4 + 1) * 4 + c]
           + w.z * ys[(g4 * 4 + 2) * 4 + c] + w.w * ys[(g4 * 4 + 3) * 4 + c];
    }
    red[t] = acc;
  }
  __syncthreads();
  if (t < 64) {
    float s = red[t] + red[64 + t] + red[128 + t] + red[192 + t];
    float bb = 0.f;
    for (int c = 0; c < 4; ++c) bb += p.eqb[c * 64 + t] * sig[c];
    ts[t] = s + bb;
  }
  __syncthreads();
  {  // z: thread (c = t>>6, g = t&63)
    int c = t >> 6, g = t & 63;
    float s = 0.f;
    for (int f = 0; f < 64; ++f) s += p.eqW[(c * 64 + f) * 64 + g] * ts[f];
    zs[c * 132 + g] = s;
  }
  if (t < 4) {
    float s = 0.f;
    for (int f = 0; f < 64; ++f) s += p.eqb[t * 64 + f] * ts[f];
    ds[t] = s;
  }
  __syncthreads();
  float lmax = -INFINITY;
  for (int rep = 0; rep < 4; ++rep) {  // scores for rows j = rep*256+t
    int j = rep * 256 + t;
    const float4* x4 = (const float4*)(p.Xe + (r0 + j) * FE_);
    float s4[4] = {ds[0], ds[1], ds[2], ds[3]};
    for (int g4 = 0; g4 < 16; ++g4) {
      float4 x = x4[g4];
#pragma unroll
      for (int c = 0; c < 4; ++c) {
        const float* z = zs + c * 132 + g4 * 4;
        s4[c] += x.x * z[0] + x.y * z[1] + x.z * z[2] + x.w * z[3];
      }
    }
    ((float4*)sc)[j] = make_float4(s4[0], s4[1], s4[2], s4[3]);
    lmax = fmaxf(lmax, fmaxf(fmaxf(s4[0], s4[1]), fmaxf(s4[2], s4[3])));
  }
  red[t] = lmax;
  __syncthreads();
  for (int off = 128; off > 0; off >>= 1) {
    if (t < off) red[t] = fmaxf(red[t], red[t + off]);
    __syncthreads();
  }
  float m = red[0];
  __syncthreads();
  float lsum = 0.f;
  for (int rep = 0; rep < 4; ++rep) {
    int j = rep * 256 + t;
    float4 v = ((float4*)sc)[j];
    v.x = expf(v.x - m); v.y = expf(v.y - m); v.z = expf(v.z - m); v.w = expf(v.w - m);
    ((float4*)sc)[j] = v;
    lsum += v.x + v.y + v.z + v.w;
  }
  red[t] = lsum;
  __syncthreads();
  for (int off = 128; off > 0; off >>= 1) {
    if (t < off) red[t] += red[t + off];
    __syncthreads();
  }
  float inv = 1.f / red[0];
  for (int rep = 0; rep < 4; ++rep) {
    int j = rep * 256 + t;
    float4 v = ((float4*)sc)[j];
    ((float4*)(p.esa + h * E_))[j] = make_float4(v.x * inv, v.y * inv, v.z * inv, v.w * inv);
  }
}

// ---------------------------------------------------------------------------
// Cooperative single-kernel path: 256 blocks x 256 threads, 3 grid syncs.
// ---------------------------------------------------------------------------
__global__ __launch_bounds__(256) void mega(P p) {
  cg::grid_group grid = cg::this_grid();
  const int t = threadIdx.x, bid = blockIdx.x;
  const int gtid = bid * 256 + t;
  __shared__ float smem[SMEM_F];

  // Phase A: init + K projections + V GEMMs
  zero_and_init(p, gtid, 65536);
  for (int idx = gtid; idx < N_ * H_ + E_ * H_; idx += 65536) kproj_item(p, idx);
  for (int T = bid; T < 384; T += 256) {
    if (T < 128)
      gemm_tile<128, false>(p.Xn, p.nvW, p.nvb, p.NV, 512, (T >> 3) * 64, (T & 7) * 64, smem, t);
    else {
      int T2 = T - 128;
      gemm_tile<64, false>(p.Xe, p.evW, p.evb, p.EV, 256, (T2 >> 2) * 64, (T2 & 3) * 64, smem, t);
    }
  }
  grid.sync();

  // Phase B: attention + winner hashing
  if (bid < 4) attn_node(p, bid, t, smem);
  else if (bid < 8) attn_edge(p, bid - 4, t, smem);
  else {
    int idx = (bid - 8) * 256 + t;
    if (idx < E_ + LE_) insert_item(p, idx);
  }
  grid.sync();

  // Phase C: sparse (proj*A) @ V scatter
  for (int idx = gtid; idx < E_ * 32; idx += 65536) scatter_node_item(p, idx);
  for (int idx = gtid; idx < LE_ * 16; idx += 65536) scatter_edge_item(p, idx);
  grid.sync();

  // Phase D: output linears + ReLU
  for (int T = bid; T < 384; T += 256) {
    if (T < 128)
      gemm_tile<128, true>(p.nagg, p.ncW, p.ncb, p.out, 128, (T >> 1) * 64, (T & 1) * 64, smem, t);
    else {
      int T2 = T - 128;
      gemm_tile<64, true>(p.eagg, p.ecW, p.ecb, p.out + (size_t)H_ * N_ * 128, 64, T2 * 64, 0, smem, t);
    }
  }
}

// ---------------------------------------------------------------------------
// Fallback regular-launch path: same device functions, 4 dispatches.
// ---------------------------------------------------------------------------
__global__ __launch_bounds__(256) void k1_prep(P p) {     // grid 448
  __shared__ float smem[4096];
  const int t = threadIdx.x, bid = blockIdx.x;
  if (bid < 128) {
    gemm_tile<128, false>(p.Xn, p.nvW, p.nvb, p.NV, 512, (bid >> 3) * 64, (bid & 7) * 64, smem, t);
  } else if (bid < 384) {
    int T2 = bid - 128;
    gemm_tile<64, false>(p.Xe, p.evW, p.evb, p.EV, 256, (T2 >> 2) * 64, (T2 & 3) * 64, smem, t);
  } else {
    int lane = (bid - 384) * 256 + t;     // 16384 lanes
    zero_and_init(p, lane, 16384);
    for (int idx = lane; idx < N_ * H_ + E_ * H_; idx += 16384) kproj_item(p, idx);
  }
}

__global__ __launch_bounds__(256) void k2_attn(P p) {     // grid 256
  __shared__ float smem[SMEM_F];
  const int t = threadIdx.x, bid = blockIdx.x;
  if (bid < 4) attn_node(p, bid, t, smem);
  else if (bid < 8) attn_edge(p, bid - 4, t, smem);
  else {
    int idx = (bid - 8) * 256 + t;
    if (idx < E_ + LE_) insert_item(p, idx);
  }
}

__global__ __launch_bounds__(256) void k3_scatter(P p) {  // grid 256
  const int gtid = blockIdx.x * 256 + threadIdx.x;
  for (int idx = gtid; idx < E_ * 32; idx += 65536) scatter_node_item(p, idx);
  for (int idx = gtid; idx < LE_ * 16; idx += 65536) scatter_edge_item(p, idx);
}

__global__ __launch_bounds__(256) void k4_out(P p) {      // grid 384
  __shared__ float smem[4096];
  const int t = threadIdx.x, bid = blockIdx.x;
  if (bid < 128)
    gemm_tile<128, true>(p.nagg, p.ncW, p.ncb, p.out, 128, (bid >> 1) * 64, (bid & 1) * 64, smem, t);
  else {
    int T2 = bid - 128;
    gemm_tile<64, true>(p.eagg, p.ecW, p.ecb, p.out + (size_t)H_ * N_ * 128, 64, T2 * 64, 0, smem, t);
  }
}

// ---------------------------------------------------------------------------
extern "C" void kernel_launch(void* const* d_in, const int* in_sizes, int n_in,
                              void* d_out, int out_size, void* d_ws, size_t ws_size,
                              hipStream_t stream) {
  P p;
  p.Xn  = (const float*)d_in[0];
  p.Xe  = (const float*)d_in[1];
  p.src = (const int*)d_in[2];
  p.dst = (const int*)d_in[3];
  p.lgs = (const int*)d_in[4];
  p.lgd = (const int*)d_in[5];
  p.nqW = (const float*)d_in[6];  p.nqb = (const float*)d_in[7];
  p.nkW = (const float*)d_in[8];  p.nkb = (const float*)d_in[9];
  p.nvW = (const float*)d_in[10]; p.nvb = (const float*)d_in[11];
  p.eqW = (const float*)d_in[12]; p.eqb = (const float*)d_in[13];
  p.ekW = (const float*)d_in[14]; p.ekb = (const float*)d_in[15];
  p.evW = (const float*)d_in[16]; p.evb = (const float*)d_in[17];
  p.ncW = (const float*)d_in[18]; p.ncb = (const float*)d_in[19];
  p.ecW = (const float*)d_in[20]; p.ecb = (const float*)d_in[21];
  p.out = (float*)d_out;

  float* f = (float*)d_ws;
  p.NV   = f; f += N_ * H_ * FN_;   // 524288
  p.EV   = f; f += E_ * H_ * FE_;   // 1048576
  p.NK   = f; f += N_ * H_;         // 4096
  p.EK   = f; f += E_ * H_;         // 16384
  p.nsa  = f; f += H_ * N_;         // 4096
  p.esa  = f; f += H_ * E_;         // 16384
  p.nagg = f; f += H_ * N_ * FN_;   // 524288  (contiguous with eagg)
  p.eagg = f; f += H_ * E_ * FE_;   // 1048576
  p.hkN  = (int*)f; f += HTN_;      // contiguous int region
  p.hvN  = (int*)f; f += HTN_;
  p.hkE  = (int*)f; f += HTE_;
  p.hvE  = (int*)f; f += HTE_;

  void* args[] = { &p };
  hipError_t err = hipLaunchCooperativeKernel((const void*)mega, dim3(256), dim3(256),
                                              args, 0, stream);
  if (err != hipSuccess) {
    (void)hipGetLastError();   // clear error state; use regular-launch pipeline
    k1_prep<<<448, 256, 0, stream>>>(p);
    k2_attn<<<256, 256, 0, stream>>>(p);
    k3_scatter<<<256, 256, 0, stream>>>(p);
    k4_out<<<384, 256, 0, stream>>>(p);
  }
}

// Round 6
// 235.734 us; speedup vs baseline: 1.5398x; 1.5398x over previous
//
#include <hip/hip_runtime.h>

#define H_ 4
#define N_ 1024
#define E_ 4096
#define LE_ 16384
#define FN_ 128
#define FE_ 64
#define HTN_ 16384   // node-pair hash slots (4x E)
#define HTE_ 65536   // line-pair hash slots (4x LE)

struct P {
  const float *Xn, *Xe;
  const int *src, *dst, *lgs, *lgd;
  const float *nqW, *nqb, *nkW, *nkb, *nvW, *nvb;
  const float *eqW, *eqb, *ekW, *ekb, *evW, *evb;
  const float *ncW, *ncb, *ecW, *ecb;
  float *out;
  float *NV, *EV, *NK, *EK, *nsa, *esa, *nagg, *eagg;
  int *hkN, *hvN, *hkE, *hvE;
};

__device__ __forceinline__ unsigned hashN(int key) {
  return (((unsigned)key * 2654435761u) >> 16) & (HTN_ - 1);
}
__device__ __forceinline__ unsigned hashE(int key) {
  return (((unsigned)key * 2654435761u) >> 16) & (HTE_ - 1);
}

// ---------------------------------------------------------------------------
// One 64x64 GEMM tile: C[r0..+64, o0..+64] = [relu](X @ W^T + b).
// XOR-swizzled k-major LDS (verified R2/R3/R5). 256 threads.
// ---------------------------------------------------------------------------
template<int K, bool RELU>
__device__ void gemm_tile(const float* __restrict__ X, const float* __restrict__ W,
                          const float* __restrict__ b, float* __restrict__ C,
                          int O, int r0, int o0, float* smem, int t) {
  float* Xs = smem;
  float* Ws = smem + 2048;
  const int tn = t & 15, tm = t >> 4;
  float acc[4][4] = {};
  for (int k0 = 0; k0 < K; k0 += 32) {
#pragma unroll
    for (int ph = 0; ph < 2; ++ph) {
      int i4 = t + ph * 256;
      int m = i4 >> 3;
      int k4 = (i4 & 7) << 2;
      int m4 = m >> 2, ml = m & 3;
      float4 vx = *(const float4*)&X[(r0 + m) * K + k0 + k4];
      float4 vw = *(const float4*)&W[(o0 + m) * K + k0 + k4];
      Xs[(k4 + 0) * 64 + ((m4 ^ ((k4 + 0) & 15)) << 2) + ml] = vx.x;
      Xs[(k4 + 1) * 64 + ((m4 ^ ((k4 + 1) & 15)) << 2) + ml] = vx.y;
      Xs[(k4 + 2) * 64 + ((m4 ^ ((k4 + 2) & 15)) << 2) + ml] = vx.z;
      Xs[(k4 + 3) * 64 + ((m4 ^ ((k4 + 3) & 15)) << 2) + ml] = vx.w;
      Ws[(k4 + 0) * 64 + ((m4 ^ ((k4 + 0) & 15)) << 2) + ml] = vw.x;
      Ws[(k4 + 1) * 64 + ((m4 ^ ((k4 + 1) & 15)) << 2) + ml] = vw.y;
      Ws[(k4 + 2) * 64 + ((m4 ^ ((k4 + 2) & 15)) << 2) + ml] = vw.z;
      Ws[(k4 + 3) * 64 + ((m4 ^ ((k4 + 3) & 15)) << 2) + ml] = vw.w;
    }
    __syncthreads();
#pragma unroll
    for (int k = 0; k < 32; ++k) {
      float4 a = *(const float4*)&Xs[k * 64 + ((tm ^ (k & 15)) << 2)];
      float4 b4 = *(const float4*)&Ws[k * 64 + ((tn ^ (k & 15)) << 2)];
      acc[0][0] += a.x * b4.x; acc[0][1] += a.x * b4.y; acc[0][2] += a.x * b4.z; acc[0][3] += a.x * b4.w;
      acc[1][0] += a.y * b4.x; acc[1][1] += a.y * b4.y; acc[1][2] += a.y * b4.z; acc[1][3] += a.y * b4.w;
      acc[2][0] += a.z * b4.x; acc[2][1] += a.z * b4.y; acc[2][2] += a.z * b4.z; acc[2][3] += a.z * b4.w;
      acc[3][0] += a.w * b4.x; acc[3][1] += a.w * b4.y; acc[3][2] += a.w * b4.z; acc[3][3] += a.w * b4.w;
    }
    __syncthreads();
  }
  float4 bv = *(const float4*)&b[o0 + tn * 4];
#pragma unroll
  for (int i = 0; i < 4; ++i) {
    float4 o;
    o.x = acc[i][0] + bv.x; o.y = acc[i][1] + bv.y;
    o.z = acc[i][2] + bv.z; o.w = acc[i][3] + bv.w;
    if (RELU) {
      o.x = fmaxf(o.x, 0.f); o.y = fmaxf(o.y, 0.f);
      o.z = fmaxf(o.z, 0.f); o.w = fmaxf(o.w, 0.f);
    }
    *(float4*)&C[(r0 + tm * 4 + i) * O + o0 + tn * 4] = o;
  }
}

// ---------------------------------------------------------------------------
// k1: V GEMMs + buffer init + tiny K projections. Grid 448 x 256.
// ---------------------------------------------------------------------------
__global__ __launch_bounds__(256) void k1_prep(P p) {
  __shared__ float smem[4096];
  const int t = threadIdx.x, bid = blockIdx.x;
  if (bid < 128) {
    gemm_tile<128, false>(p.Xn, p.nvW, p.nvb, p.NV, 512, (bid >> 3) * 64, (bid & 7) * 64, smem, t);
  } else if (bid < 384) {
    int T2 = bid - 128;
    gemm_tile<64, false>(p.Xe, p.evW, p.evb, p.EV, 256, (T2 >> 2) * 64, (T2 & 3) * 64, smem, t);
  } else {
    int lane = (bid - 384) * 256 + t;     // 16384 lanes
    float4 z4 = make_float4(0.f, 0.f, 0.f, 0.f);
    float4* zb = (float4*)p.nagg;         // nagg+eagg contiguous: 1572864 floats
    for (int i = lane; i < 1572864 / 4; i += 16384) zb[i] = z4;
    int4 m4 = make_int4(-1, -1, -1, -1);
    int4* hb = (int4*)p.hkN;              // hkN,hvN,hkE,hvE contiguous: 163840 ints
    for (int i = lane; i < 163840 / 4; i += 16384) hb[i] = m4;
    for (int idx = lane; idx < N_ * H_ + E_ * H_; idx += 16384) {
      if (idx < N_ * H_) {
        int r = idx >> 2, o = idx & 3;
        const float4* x4 = (const float4*)(p.Xn + r * FN_);
        const float4* w4 = (const float4*)(p.nkW + o * FN_);
        float acc = p.nkb[o];
        for (int k = 0; k < 32; ++k) {
          float4 x = x4[k], w = w4[k];
          acc += x.x * w.x + x.y * w.y + x.z * w.z + x.w * w.w;
        }
        p.NK[idx] = acc;
      } else {
        int j = idx - N_ * H_;
        int r = j >> 2, o = j & 3;
        const float4* x4 = (const float4*)(p.Xe + r * FE_);
        const float4* w4 = (const float4*)(p.ekW + o * FE_);
        float acc = p.ekb[o];
        for (int k = 0; k < 16; ++k) {
          float4 x = x4[k], w = w4[k];
          acc += x.x * w.x + x.y * w.y + x.z * w.z + x.w * w.w;
        }
        p.EK[j] = acc;
      }
    }
  }
}

// ---------------------------------------------------------------------------
// k2: factored attention (R3-verified, 1024 threads) + winner hash inserts.
// Blocks 0..3 node heads, 4..7 edge heads, 8..27 inserts. Grid 28 x 1024.
// position i = 4j + c <-> lin row r = rowbase + j, weight slice c.
//   y_c[g] = sum_j X[r,g]*Klin[r,c];  sigma_c = sum_j Klin[r,c]
//   t[f]   = sum_c ( Wq_c[f,:].y_c + sigma_c*b_c[f] )
//   z_c[g] = sum_f Wq[c*F+f,g]*t[f]; d_c = sum_f b_c[f] t[f]
//   s[4j+c]= X[r,:].z_c + d_c  -> softmax over positions
// ---------------------------------------------------------------------------
__global__ __launch_bounds__(1024) void k2_attn(P p) {
  __shared__ float4 accs[1024];
  __shared__ float red[1024];
  __shared__ float ys[512];
  __shared__ float ts[128];
  __shared__ float zs[4 * 132];
  __shared__ float ds[4], sig[4];
  const int tid = threadIdx.x;

  if (blockIdx.x >= 8) {   // hash inserts: lanes cover E+LE = 20480 exactly
    int idx = (blockIdx.x - 8) * 1024 + tid;
    if (idx < E_) {
      int key = p.src[idx] * N_ + p.dst[idx];
      unsigned slot = hashN(key);
      while (true) {
        int prev = atomicCAS(&p.hkN[slot], -1, key);
        if (prev == -1 || prev == key) break;
        slot = (slot + 1) & (HTN_ - 1);
      }
      atomicMax(&p.hvN[slot], idx);
    } else if (idx < E_ + LE_) {
      int l = idx - E_;
      int key = p.lgs[l] * E_ + p.lgd[l];
      unsigned slot = hashE(key);
      while (true) {
        int prev = atomicCAS(&p.hkE[slot], -1, key);
        if (prev == -1 || prev == key) break;
        slot = (slot + 1) & (HTE_ - 1);
      }
      atomicMax(&p.hvE[slot], l);
    }
    return;
  }

  if (blockIdx.x < 4) {
    // ---------------- node head ----------------
    const int h = blockIdx.x;
    const int r0 = h * 256;
    {
      int g = tid & 127, q = tid >> 7;      // 8 chunks x 32 rows
      float a0 = 0, a1 = 0, a2 = 0, a3 = 0;
      for (int jj = 0; jj < 32; ++jj) {
        int r = r0 + q * 32 + jj;
        float x = p.Xn[r * FN_ + g];
        float4 k = ((const float4*)p.NK)[r];
        a0 += x * k.x; a1 += x * k.y; a2 += x * k.z; a3 += x * k.w;
      }
      accs[tid] = make_float4(a0, a1, a2, a3);
    }
    __syncthreads();
    for (int off = 512; off >= 128; off >>= 1) {
      if (tid < off) {
        float4 a = accs[tid], b = accs[tid + off];
        accs[tid] = make_float4(a.x + b.x, a.y + b.y, a.z + b.z, a.w + b.w);
      }
      __syncthreads();
    }
    if (tid < 128) {
      float4 a = accs[tid];
      ys[tid * 4 + 0] = a.x; ys[tid * 4 + 1] = a.y;
      ys[tid * 4 + 2] = a.z; ys[tid * 4 + 3] = a.w;
    }
    if (tid >= 128 && tid < 160) {
      int t2 = tid - 128, c = t2 & 3, part = t2 >> 2;
      float s = 0.f;
      for (int j = 0; j < 32; ++j) s += p.NK[(r0 + part * 32 + j) * 4 + c];
      red[t2] = s;
    }
    __syncthreads();
    if (tid < 4) { float s = 0.f; for (int q = 0; q < 8; ++q) s += red[q * 4 + tid]; sig[tid] = s; }
    __syncthreads();
    if (tid < 512) {   // t[f] partials: row tid = c*128+f of nqW
      const float4* w4 = (const float4*)(p.nqW + tid * FN_);
      int c = tid >> 7;
      float s = 0.f;
      for (int g4 = 0; g4 < 32; ++g4) {
        float4 w = w4[g4];
        s += w.x * ys[(g4 * 4 + 0) * 4 + c] + w.y * ys[(g4 * 4 + 1) * 4 + c]
           + w.z * ys[(g4 * 4 + 2) * 4 + c] + w.w * ys[(g4 * 4 + 3) * 4 + c];
      }
      red[tid] = s;
    }
    __syncthreads();
    if (tid < 128) {
      float s = red[tid] + red[128 + tid] + red[256 + tid] + red[384 + tid];
      float bb = 0.f;
      for (int c = 0; c < 4; ++c) bb += p.nqb[c * 128 + tid] * sig[c];
      ts[tid] = s + bb;
    }
    __syncthreads();
    if (tid < 512) {   // z: c = tid>>7, g = tid&127
      int c = tid >> 7, g = tid & 127;
      float s = 0.f;
      for (int f = 0; f < 128; ++f) s += p.nqW[(c * 128 + f) * 128 + g] * ts[f];
      zs[c * 132 + g] = s;
    }
    if (tid >= 512 && tid < 516) {
      int c = tid - 512;
      float s = 0.f;
      for (int f = 0; f < 128; ++f) s += p.nqb[c * 128 + f] * ts[f];
      ds[c] = s;
    }
    __syncthreads();
    float sc;
    {   // scores: thread = position i = 4j+c
      int c = tid & 3, j = tid >> 2;
      const float4* x4 = (const float4*)(p.Xn + (r0 + j) * FN_);
      const float* z = zs + c * 132;
      float s = ds[c];
      for (int g4 = 0; g4 < 32; ++g4) {
        float4 x = x4[g4];
        s += x.x * z[g4 * 4] + x.y * z[g4 * 4 + 1] + x.z * z[g4 * 4 + 2] + x.w * z[g4 * 4 + 3];
      }
      sc = s;
    }
    red[tid] = sc;
    __syncthreads();
    for (int off = 512; off > 0; off >>= 1) {
      if (tid < off) red[tid] = fmaxf(red[tid], red[tid + off]);
      __syncthreads();
    }
    float m = red[0];
    __syncthreads();
    float e = expf(sc - m);
    red[tid] = e;
    __syncthreads();
    for (int off = 512; off > 0; off >>= 1) {
      if (tid < off) red[tid] += red[tid + off];
      __syncthreads();
    }
    p.nsa[h * N_ + tid] = e / red[0];
  } else {
    // ---------------- edge head ----------------
    const int h = blockIdx.x - 4;
    const int r0 = h * 1024;
    {
      int g = tid & 63, q = tid >> 6;      // 16 chunks x 64 rows
      float a0 = 0, a1 = 0, a2 = 0, a3 = 0;
      for (int jj = 0; jj < 64; ++jj) {
        int r = r0 + q * 64 + jj;
        float x = p.Xe[r * FE_ + g];
        float4 k = ((const float4*)p.EK)[r];
        a0 += x * k.x; a1 += x * k.y; a2 += x * k.z; a3 += x * k.w;
      }
      accs[tid] = make_float4(a0, a1, a2, a3);
    }
    __syncthreads();
    for (int off = 512; off >= 64; off >>= 1) {
      if (tid < off) {
        float4 a = accs[tid], b = accs[tid + off];
        accs[tid] = make_float4(a.x + b.x, a.y + b.y, a.z + b.z, a.w + b.w);
      }
      __syncthreads();
    }
    if (tid < 64) {
      float4 a = accs[tid];
      ys[tid * 4 + 0] = a.x; ys[tid * 4 + 1] = a.y;
      ys[tid * 4 + 2] = a.z; ys[tid * 4 + 3] = a.w;
    }
    if (tid >= 128 && tid < 160) {
      int t2 = tid - 128, c = t2 & 3, part = t2 >> 2;
      float s = 0.f;
      for (int j = 0; j < 128; ++j) s += p.EK[(r0 + part * 128 + j) * 4 + c];
      red[t2] = s;
    }
    __syncthreads();
    if (tid < 4) { float s = 0.f; for (int q = 0; q < 8; ++q) s += red[q * 4 + tid]; sig[tid] = s; }
    __syncthreads();
    if (tid < 256) {   // t[f] partials: row tid = c*64+f of eqW
      const float4* w4 = (const float4*)(p.eqW + tid * FE_);
      int c = tid >> 6;
      float s = 0.f;
      for (int g4 = 0; g4 < 16; ++g4) {
        float4 w = w4[g4];
        s += w.x * ys[(g4 * 4 + 0) * 4 + c] + w.y * ys[(g4 * 4 + 1) * 4 + c]
           + w.z * ys[(g4 * 4 + 2) * 4 + c] + w.w * ys[(g4 * 4 + 3) * 4 + c];
      }
      red[tid] = s;
    }
    __syncthreads();
    if (tid < 64) {
      float s = red[tid] + red[64 + tid] + red[128 + tid] + red[192 + tid];
      float bb = 0.f;
      for (int c = 0; c < 4; ++c) bb += p.eqb[c * 64 + tid] * sig[c];
      ts[tid] = s + bb;
    }
    __syncthreads();
    if (tid < 256) {   // z: c = tid>>6, g = tid&63
      int c = tid >> 6, g = tid & 63;
      float s = 0.f;
      for (int f = 0; f < 64; ++f) s += p.eqW[(c * 64 + f) * 64 + g] * ts[f];
      zs[c * 132 + g] = s;
    }
    if (tid >= 256 && tid < 260) {
      int c = tid - 256;
      float s = 0.f;
      for (int f = 0; f < 64; ++f) s += p.eqb[c * 64 + f] * ts[f];
      ds[c] = s;
    }
    __syncthreads();
    float s4[4];
    {   // scores: thread j handles positions 4j..4j+3 (one Xe row)
      const float4* x4 = (const float4*)(p.Xe + (r0 + tid) * FE_);
      s4[0] = ds[0]; s4[1] = ds[1]; s4[2] = ds[2]; s4[3] = ds[3];
      for (int g4 = 0; g4 < 16; ++g4) {
        float4 x = x4[g4];
#pragma unroll
        for (int c = 0; c < 4; ++c) {
          const float* z = zs + c * 132 + g4 * 4;
          s4[c] += x.x * z[0] + x.y * z[1] + x.z * z[2] + x.w * z[3];
        }
      }
    }
    float lm = fmaxf(fmaxf(s4[0], s4[1]), fmaxf(s4[2], s4[3]));
    red[tid] = lm;
    __syncthreads();
    for (int off = 512; off > 0; off >>= 1) {
      if (tid < off) red[tid] = fmaxf(red[tid], red[tid + off]);
      __syncthreads();
    }
    float m = red[0];
    __syncthreads();
    float e0 = expf(s4[0] - m), e1 = expf(s4[1] - m);
    float e2 = expf(s4[2] - m), e3 = expf(s4[3] - m);
    red[tid] = e0 + e1 + e2 + e3;
    __syncthreads();
    for (int off = 512; off > 0; off >>= 1) {
      if (tid < off) red[tid] += red[tid + off];
      __syncthreads();
    }
    float inv = 1.f / red[0];
    ((float4*)(p.esa + h * E_))[tid] = make_float4(e0 * inv, e1 * inv, e2 * inv, e3 * inv);
  }
}

// ---------------------------------------------------------------------------
// k3: sparse (proj*A) @ V scatter with NATIVE fp32 atomics (fire-and-forget).
// Grid 1536 x 256; idx < E*32 -> node item (e, f4); else edge item (l, f4).
// ---------------------------------------------------------------------------
__global__ __launch_bounds__(256) void k3_scatter(P p) {
  int idx = blockIdx.x * 256 + threadIdx.x;
  if (idx < E_ * 32) {
    int e = idx >> 5, f4 = idx & 31;
    int s = p.src[e], d = p.dst[e];
    int key = s * N_ + d;
    unsigned slot = hashN(key);
    while (p.hkN[slot] != key) slot = (slot + 1) & (HTN_ - 1);
    if (p.hvN[slot] != e) return;
#pragma unroll
    for (int h = 0; h < H_; ++h) {
      float a = p.esa[h * E_ + e];
      float4 v = ((const float4*)(p.NV + h * (N_ * FN_) + d * FN_))[f4];
      float* dp = p.nagg + h * (N_ * FN_) + s * FN_ + f4 * 4;
      unsafeAtomicAdd(dp + 0, a * v.x); unsafeAtomicAdd(dp + 1, a * v.y);
      unsafeAtomicAdd(dp + 2, a * v.z); unsafeAtomicAdd(dp + 3, a * v.w);
    }
  } else {
    idx -= E_ * 32;
    int l = idx >> 4, f4 = idx & 15;
    int j = p.lgs[l], c = p.lgd[l];
    int key = j * E_ + c;
    unsigned slot = hashE(key);
    while (p.hkE[slot] != key) slot = (slot + 1) & (HTE_ - 1);
    if (p.hvE[slot] != l) return;
    int cn = p.dst[j];
#pragma unroll
    for (int h = 0; h < H_; ++h) {
      float a = p.nsa[h * N_ + cn];
      float4 v = ((const float4*)(p.EV + h * (E_ * FE_) + c * FE_))[f4];
      float* dp = p.eagg + h * (E_ * FE_) + j * FE_ + f4 * 4;
      unsafeAtomicAdd(dp + 0, a * v.x); unsafeAtomicAdd(dp + 1, a * v.y);
      unsafeAtomicAdd(dp + 2, a * v.z); unsafeAtomicAdd(dp + 3, a * v.w);
    }
  }
}

// ---------------------------------------------------------------------------
// k4: output linears + ReLU into d_out. Grid 384 x 256.
// ---------------------------------------------------------------------------
__global__ __launch_bounds__(256) void k4_out(P p) {
  __shared__ float smem[4096];
  const int t = threadIdx.x, bid = blockIdx.x;
  if (bid < 128)
    gemm_tile<128, true>(p.nagg, p.ncW, p.ncb, p.out, 128, (bid >> 1) * 64, (bid & 1) * 64, smem, t);
  else {
    int T2 = bid - 128;
    gemm_tile<64, true>(p.eagg, p.ecW, p.ecb, p.out + (size_t)H_ * N_ * 128, 64, T2 * 64, 0, smem, t);
  }
}

// ---------------------------------------------------------------------------
extern "C" void kernel_launch(void* const* d_in, const int* in_sizes, int n_in,
                              void* d_out, int out_size, void* d_ws, size_t ws_size,
                              hipStream_t stream) {
  P p;
  p.Xn  = (const float*)d_in[0];
  p.Xe  = (const float*)d_in[1];
  p.src = (const int*)d_in[2];
  p.dst = (const int*)d_in[3];
  p.lgs = (const int*)d_in[4];
  p.lgd = (const int*)d_in[5];
  p.nqW = (const float*)d_in[6];  p.nqb = (const float*)d_in[7];
  p.nkW = (const float*)d_in[8];  p.nkb = (const float*)d_in[9];
  p.nvW = (const float*)d_in[10]; p.nvb = (const float*)d_in[11];
  p.eqW = (const float*)d_in[12]; p.eqb = (const float*)d_in[13];
  p.ekW = (const float*)d_in[14]; p.ekb = (const float*)d_in[15];
  p.evW = (const float*)d_in[16]; p.evb = (const float*)d_in[17];
  p.ncW = (const float*)d_in[18]; p.ncb = (const float*)d_in[19];
  p.ecW = (const float*)d_in[20]; p.ecb = (const float*)d_in[21];
  p.out = (float*)d_out;

  float* f = (float*)d_ws;
  p.NV   = f; f += N_ * H_ * FN_;   // 524288
  p.EV   = f; f += E_ * H_ * FE_;   // 1048576
  p.NK   = f; f += N_ * H_;         // 4096
  p.EK   = f; f += E_ * H_;         // 16384
  p.nsa  = f; f += H_ * N_;         // 4096
  p.esa  = f; f += H_ * E_;         // 16384
  p.nagg = f; f += H_ * N_ * FN_;   // 524288  (contiguous with eagg)
  p.eagg = f; f += H_ * E_ * FE_;   // 1048576
  p.hkN  = (int*)f; f += HTN_;      // contiguous int region
  p.hvN  = (int*)f; f += HTN_;
  p.hkE  = (int*)f; f += HTE_;
  p.hvE  = (int*)f; f += HTE_;

  k1_prep<<<448, 256, 0, stream>>>(p);
  k2_attn<<<28, 1024, 0, stream>>>(p);
  k3_scatter<<<1536, 256, 0, stream>>>(p);
  k4_out<<<384, 256, 0, stream>>>(p);
}

// Round 7
// 162.981 us; speedup vs baseline: 2.2272x; 1.4464x over previous
//
#include <hip/hip_runtime.h>

#define H_ 4
#define N_ 1024
#define E_ 4096
#define LE_ 16384
#define FN_ 128
#define FE_ 64
#define HTN_ 16384   // node-pair hash slots (4x E)
#define HTE_ 65536   // line-pair hash slots (4x LE)
#define CAP_ 32      // per-source adjacency capacity (avg deg 4, P(>32) ~ 1e-18)

struct P {
  const float *Xn, *Xe;
  const int *src, *dst, *lgs, *lgd;
  const float *nqW, *nqb, *nkW, *nkb, *nvW, *nvb;
  const float *eqW, *eqb, *ekW, *ekb, *evW, *evb;
  const float *ncW, *ncb, *ecW, *ecb;
  float *out;
  float *NV, *EV, *NK, *EK, *nsa, *esa, *nagg, *eagg;
  int *hkN, *hvN, *hkE, *hvE;
  int *cntN, *cntE, *listN, *listE;
};

__device__ __forceinline__ unsigned hashN(int key) {
  return (((unsigned)key * 2654435761u) >> 16) & (HTN_ - 1);
}
__device__ __forceinline__ unsigned hashE(int key) {
  return (((unsigned)key * 2654435761u) >> 16) & (HTE_ - 1);
}

// ---------------------------------------------------------------------------
// One 64x64 GEMM tile: C[r0..+64, o0..+64] = [relu](X @ W^T + b).
// XOR-swizzled k-major LDS (verified R2/R3/R5/R6). 256 threads.
// ---------------------------------------------------------------------------
template<int K, bool RELU>
__device__ void gemm_tile(const float* __restrict__ X, const float* __restrict__ W,
                          const float* __restrict__ b, float* __restrict__ C,
                          int O, int r0, int o0, float* smem, int t) {
  float* Xs = smem;
  float* Ws = smem + 2048;
  const int tn = t & 15, tm = t >> 4;
  float acc[4][4] = {};
  for (int k0 = 0; k0 < K; k0 += 32) {
#pragma unroll
    for (int ph = 0; ph < 2; ++ph) {
      int i4 = t + ph * 256;
      int m = i4 >> 3;
      int k4 = (i4 & 7) << 2;
      int m4 = m >> 2, ml = m & 3;
      float4 vx = *(const float4*)&X[(r0 + m) * K + k0 + k4];
      float4 vw = *(const float4*)&W[(o0 + m) * K + k0 + k4];
      Xs[(k4 + 0) * 64 + ((m4 ^ ((k4 + 0) & 15)) << 2) + ml] = vx.x;
      Xs[(k4 + 1) * 64 + ((m4 ^ ((k4 + 1) & 15)) << 2) + ml] = vx.y;
      Xs[(k4 + 2) * 64 + ((m4 ^ ((k4 + 2) & 15)) << 2) + ml] = vx.z;
      Xs[(k4 + 3) * 64 + ((m4 ^ ((k4 + 3) & 15)) << 2) + ml] = vx.w;
      Ws[(k4 + 0) * 64 + ((m4 ^ ((k4 + 0) & 15)) << 2) + ml] = vw.x;
      Ws[(k4 + 1) * 64 + ((m4 ^ ((k4 + 1) & 15)) << 2) + ml] = vw.y;
      Ws[(k4 + 2) * 64 + ((m4 ^ ((k4 + 2) & 15)) << 2) + ml] = vw.z;
      Ws[(k4 + 3) * 64 + ((m4 ^ ((k4 + 3) & 15)) << 2) + ml] = vw.w;
    }
    __syncthreads();
#pragma unroll
    for (int k = 0; k < 32; ++k) {
      float4 a = *(const float4*)&Xs[k * 64 + ((tm ^ (k & 15)) << 2)];
      float4 b4 = *(const float4*)&Ws[k * 64 + ((tn ^ (k & 15)) << 2)];
      acc[0][0] += a.x * b4.x; acc[0][1] += a.x * b4.y; acc[0][2] += a.x * b4.z; acc[0][3] += a.x * b4.w;
      acc[1][0] += a.y * b4.x; acc[1][1] += a.y * b4.y; acc[1][2] += a.y * b4.z; acc[1][3] += a.y * b4.w;
      acc[2][0] += a.z * b4.x; acc[2][1] += a.z * b4.y; acc[2][2] += a.z * b4.z; acc[2][3] += a.z * b4.w;
      acc[3][0] += a.w * b4.x; acc[3][1] += a.w * b4.y; acc[3][2] += a.w * b4.z; acc[3][3] += a.w * b4.w;
    }
    __syncthreads();
  }
  float4 bv = *(const float4*)&b[o0 + tn * 4];
#pragma unroll
  for (int i = 0; i < 4; ++i) {
    float4 o;
    o.x = acc[i][0] + bv.x; o.y = acc[i][1] + bv.y;
    o.z = acc[i][2] + bv.z; o.w = acc[i][3] + bv.w;
    if (RELU) {
      o.x = fmaxf(o.x, 0.f); o.y = fmaxf(o.y, 0.f);
      o.z = fmaxf(o.z, 0.f); o.w = fmaxf(o.w, 0.f);
    }
    *(float4*)&C[(r0 + tm * 4 + i) * O + o0 + tn * 4] = o;
  }
}

// ---------------------------------------------------------------------------
// k1: V GEMMs + hash/counter init + tiny K projections. Grid 448 x 256.
// (nagg/eagg need NO zero-init anymore: k5_gather overwrites every element.)
// ---------------------------------------------------------------------------
__global__ __launch_bounds__(256) void k1_prep(P p) {
  __shared__ float smem[4096];
  const int t = threadIdx.x, bid = blockIdx.x;
  if (bid < 128) {
    gemm_tile<128, false>(p.Xn, p.nvW, p.nvb, p.NV, 512, (bid >> 3) * 64, (bid & 7) * 64, smem, t);
  } else if (bid < 384) {
    int T2 = bid - 128;
    gemm_tile<64, false>(p.Xe, p.evW, p.evb, p.EV, 256, (T2 >> 2) * 64, (T2 & 3) * 64, smem, t);
  } else {
    int lane = (bid - 384) * 256 + t;     // 16384 lanes
    int4 m4 = make_int4(-1, -1, -1, -1);
    int4* hb = (int4*)p.hkN;              // hkN,hvN,hkE,hvE contiguous: 163840 ints
    for (int i = lane; i < 163840 / 4; i += 16384) hb[i] = m4;
    if (lane < N_ + E_) {                 // zero adjacency counters (5120 ints)
      if (lane < N_) p.cntN[lane] = 0;
      else p.cntE[lane - N_] = 0;
    }
    for (int idx = lane; idx < N_ * H_ + E_ * H_; idx += 16384) {
      if (idx < N_ * H_) {
        int r = idx >> 2, o = idx & 3;
        const float4* x4 = (const float4*)(p.Xn + r * FN_);
        const float4* w4 = (const float4*)(p.nkW + o * FN_);
        float acc = p.nkb[o];
        for (int k = 0; k < 32; ++k) {
          float4 x = x4[k], w = w4[k];
          acc += x.x * w.x + x.y * w.y + x.z * w.z + x.w * w.w;
        }
        p.NK[idx] = acc;
      } else {
        int j = idx - N_ * H_;
        int r = j >> 2, o = j & 3;
        const float4* x4 = (const float4*)(p.Xe + r * FE_);
        const float4* w4 = (const float4*)(p.ekW + o * FE_);
        float acc = p.ekb[o];
        for (int k = 0; k < 16; ++k) {
          float4 x = x4[k], w = w4[k];
          acc += x.x * w.x + x.y * w.y + x.z * w.z + x.w * w.w;
        }
        p.EK[j] = acc;
      }
    }
  }
}

// ---------------------------------------------------------------------------
// k2: factored attention (R3-verified, 1024 threads) + winner hash inserts.
// Blocks 0..3 node heads, 4..7 edge heads, 8..27 inserts. Grid 28 x 1024.
//   y_c[g] = sum_j X[r,g]*Klin[r,c];  sigma_c = sum_j Klin[r,c]
//   t[f]   = sum_c ( Wq_c[f,:].y_c + sigma_c*b_c[f] )
//   z_c[g] = sum_f Wq[c*F+f,g]*t[f]; d_c = sum_f b_c[f] t[f]
//   s[4j+c]= X[r,:].z_c + d_c  -> softmax over positions
// ---------------------------------------------------------------------------
__global__ __launch_bounds__(1024) void k2_attn(P p) {
  __shared__ float4 accs[1024];
  __shared__ float red[1024];
  __shared__ float ys[512];
  __shared__ float ts[128];
  __shared__ float zs[4 * 132];
  __shared__ float ds[4], sig[4];
  const int tid = threadIdx.x;

  if (blockIdx.x >= 8) {   // hash inserts: lanes cover E+LE = 20480 exactly
    int idx = (blockIdx.x - 8) * 1024 + tid;
    if (idx < E_) {
      int key = p.src[idx] * N_ + p.dst[idx];
      unsigned slot = hashN(key);
      while (true) {
        int prev = atomicCAS(&p.hkN[slot], -1, key);
        if (prev == -1 || prev == key) break;
        slot = (slot + 1) & (HTN_ - 1);
      }
      atomicMax(&p.hvN[slot], idx);
    } else if (idx < E_ + LE_) {
      int l = idx - E_;
      int key = p.lgs[l] * E_ + p.lgd[l];
      unsigned slot = hashE(key);
      while (true) {
        int prev = atomicCAS(&p.hkE[slot], -1, key);
        if (prev == -1 || prev == key) break;
        slot = (slot + 1) & (HTE_ - 1);
      }
      atomicMax(&p.hvE[slot], l);
    }
    return;
  }

  if (blockIdx.x < 4) {
    // ---------------- node head ----------------
    const int h = blockIdx.x;
    const int r0 = h * 256;
    {
      int g = tid & 127, q = tid >> 7;      // 8 chunks x 32 rows
      float a0 = 0, a1 = 0, a2 = 0, a3 = 0;
      for (int jj = 0; jj < 32; ++jj) {
        int r = r0 + q * 32 + jj;
        float x = p.Xn[r * FN_ + g];
        float4 k = ((const float4*)p.NK)[r];
        a0 += x * k.x; a1 += x * k.y; a2 += x * k.z; a3 += x * k.w;
      }
      accs[tid] = make_float4(a0, a1, a2, a3);
    }
    __syncthreads();
    for (int off = 512; off >= 128; off >>= 1) {
      if (tid < off) {
        float4 a = accs[tid], b = accs[tid + off];
        accs[tid] = make_float4(a.x + b.x, a.y + b.y, a.z + b.z, a.w + b.w);
      }
      __syncthreads();
    }
    if (tid < 128) {
      float4 a = accs[tid];
      ys[tid * 4 + 0] = a.x; ys[tid * 4 + 1] = a.y;
      ys[tid * 4 + 2] = a.z; ys[tid * 4 + 3] = a.w;
    }
    if (tid >= 128 && tid < 160) {
      int t2 = tid - 128, c = t2 & 3, part = t2 >> 2;
      float s = 0.f;
      for (int j = 0; j < 32; ++j) s += p.NK[(r0 + part * 32 + j) * 4 + c];
      red[t2] = s;
    }
    __syncthreads();
    if (tid < 4) { float s = 0.f; for (int q = 0; q < 8; ++q) s += red[q * 4 + tid]; sig[tid] = s; }
    __syncthreads();
    if (tid < 512) {   // t[f] partials: row tid = c*128+f of nqW
      const float4* w4 = (const float4*)(p.nqW + tid * FN_);
      int c = tid >> 7;
      float s = 0.f;
      for (int g4 = 0; g4 < 32; ++g4) {
        float4 w = w4[g4];
        s += w.x * ys[(g4 * 4 + 0) * 4 + c] + w.y * ys[(g4 * 4 + 1) * 4 + c]
           + w.z * ys[(g4 * 4 + 2) * 4 + c] + w.w * ys[(g4 * 4 + 3) * 4 + c];
      }
      red[tid] = s;
    }
    __syncthreads();
    if (tid < 128) {
      float s = red[tid] + red[128 + tid] + red[256 + tid] + red[384 + tid];
      float bb = 0.f;
      for (int c = 0; c < 4; ++c) bb += p.nqb[c * 128 + tid] * sig[c];
      ts[tid] = s + bb;
    }
    __syncthreads();
    if (tid < 512) {   // z: c = tid>>7, g = tid&127
      int c = tid >> 7, g = tid & 127;
      float s = 0.f;
      for (int f = 0; f < 128; ++f) s += p.nqW[(c * 128 + f) * 128 + g] * ts[f];
      zs[c * 132 + g] = s;
    }
    if (tid >= 512 && tid < 516) {
      int c = tid - 512;
      float s = 0.f;
      for (int f = 0; f < 128; ++f) s += p.nqb[c * 128 + f] * ts[f];
      ds[c] = s;
    }
    __syncthreads();
    float sc;
    {   // scores: thread = position i = 4j+c
      int c = tid & 3, j = tid >> 2;
      const float4* x4 = (const float4*)(p.Xn + (r0 + j) * FN_);
      const float* z = zs + c * 132;
      float s = ds[c];
      for (int g4 = 0; g4 < 32; ++g4) {
        float4 x = x4[g4];
        s += x.x * z[g4 * 4] + x.y * z[g4 * 4 + 1] + x.z * z[g4 * 4 + 2] + x.w * z[g4 * 4 + 3];
      }
      sc = s;
    }
    red[tid] = sc;
    __syncthreads();
    for (int off = 512; off > 0; off >>= 1) {
      if (tid < off) red[tid] = fmaxf(red[tid], red[tid + off]);
      __syncthreads();
    }
    float m = red[0];
    __syncthreads();
    float e = expf(sc - m);
    red[tid] = e;
    __syncthreads();
    for (int off = 512; off > 0; off >>= 1) {
      if (tid < off) red[tid] += red[tid + off];
      __syncthreads();
    }
    p.nsa[h * N_ + tid] = e / red[0];
  } else {
    // ---------------- edge head ----------------
    const int h = blockIdx.x - 4;
    const int r0 = h * 1024;
    {
      int g = tid & 63, q = tid >> 6;      // 16 chunks x 64 rows
      float a0 = 0, a1 = 0, a2 = 0, a3 = 0;
      for (int jj = 0; jj < 64; ++jj) {
        int r = r0 + q * 64 + jj;
        float x = p.Xe[r * FE_ + g];
        float4 k = ((const float4*)p.EK)[r];
        a0 += x * k.x; a1 += x * k.y; a2 += x * k.z; a3 += x * k.w;
      }
      accs[tid] = make_float4(a0, a1, a2, a3);
    }
    __syncthreads();
    for (int off = 512; off >= 64; off >>= 1) {
      if (tid < off) {
        float4 a = accs[tid], b = accs[tid + off];
        accs[tid] = make_float4(a.x + b.x, a.y + b.y, a.z + b.z, a.w + b.w);
      }
      __syncthreads();
    }
    if (tid < 64) {
      float4 a = accs[tid];
      ys[tid * 4 + 0] = a.x; ys[tid * 4 + 1] = a.y;
      ys[tid * 4 + 2] = a.z; ys[tid * 4 + 3] = a.w;
    }
    if (tid >= 128 && tid < 160) {
      int t2 = tid - 128, c = t2 & 3, part = t2 >> 2;
      float s = 0.f;
      for (int j = 0; j < 128; ++j) s += p.EK[(r0 + part * 128 + j) * 4 + c];
      red[t2] = s;
    }
    __syncthreads();
    if (tid < 4) { float s = 0.f; for (int q = 0; q < 8; ++q) s += red[q * 4 + tid]; sig[tid] = s; }
    __syncthreads();
    if (tid < 256) {   // t[f] partials: row tid = c*64+f of eqW
      const float4* w4 = (const float4*)(p.eqW + tid * FE_);
      int c = tid >> 6;
      float s = 0.f;
      for (int g4 = 0; g4 < 16; ++g4) {
        float4 w = w4[g4];
        s += w.x * ys[(g4 * 4 + 0) * 4 + c] + w.y * ys[(g4 * 4 + 1) * 4 + c]
           + w.z * ys[(g4 * 4 + 2) * 4 + c] + w.w * ys[(g4 * 4 + 3) * 4 + c];
      }
      red[tid] = s;
    }
    __syncthreads();
    if (tid < 64) {
      float s = red[tid] + red[64 + tid] + red[128 + tid] + red[192 + tid];
      float bb = 0.f;
      for (int c = 0; c < 4; ++c) bb += p.eqb[c * 64 + tid] * sig[c];
      ts[tid] = s + bb;
    }
    __syncthreads();
    if (tid < 256) {   // z: c = tid>>6, g = tid&63
      int c = tid >> 6, g = tid & 63;
      float s = 0.f;
      for (int f = 0; f < 64; ++f) s += p.eqW[(c * 64 + f) * 64 + g] * ts[f];
      zs[c * 132 + g] = s;
    }
    if (tid >= 256 && tid < 260) {
      int c = tid - 256;
      float s = 0.f;
      for (int f = 0; f < 64; ++f) s += p.eqb[c * 64 + f] * ts[f];
      ds[c] = s;
    }
    __syncthreads();
    float s4[4];
    {   // scores: thread j handles positions 4j..4j+3 (one Xe row)
      const float4* x4 = (const float4*)(p.Xe + (r0 + tid) * FE_);
      s4[0] = ds[0]; s4[1] = ds[1]; s4[2] = ds[2]; s4[3] = ds[3];
      for (int g4 = 0; g4 < 16; ++g4) {
        float4 x = x4[g4];
#pragma unroll
        for (int c = 0; c < 4; ++c) {
          const float* z = zs + c * 132 + g4 * 4;
          s4[c] += x.x * z[0] + x.y * z[1] + x.z * z[2] + x.w * z[3];
        }
      }
    }
    float lm = fmaxf(fmaxf(s4[0], s4[1]), fmaxf(s4[2], s4[3]));
    red[tid] = lm;
    __syncthreads();
    for (int off = 512; off > 0; off >>= 1) {
      if (tid < off) red[tid] = fmaxf(red[tid], red[tid + off]);
      __syncthreads();
    }
    float m = red[0];
    __syncthreads();
    float e0 = expf(s4[0] - m), e1 = expf(s4[1] - m);
    float e2 = expf(s4[2] - m), e3 = expf(s4[3] - m);
    red[tid] = e0 + e1 + e2 + e3;
    __syncthreads();
    for (int off = 512; off > 0; off >>= 1) {
      if (tid < off) red[tid] += red[tid + off];
      __syncthreads();
    }
    float inv = 1.f / red[0];
    ((float4*)(p.esa + h * E_))[tid] = make_float4(e0 * inv, e1 * inv, e2 * inv, e3 * inv);
  }
}

// ---------------------------------------------------------------------------
// k3: build winner adjacency lists (gather-ready CSR with fixed capacity).
// Node list packs (dst<<12 | e); edge list stores lgd only (nsa factor is
// row-uniform). Only ~20K int atomics. Grid 80 x 256 = E + LE lanes.
// ---------------------------------------------------------------------------
__global__ __launch_bounds__(256) void k3_build(P p) {
  int idx = blockIdx.x * 256 + threadIdx.x;
  if (idx < E_) {
    int e = idx;
    int s = p.src[e], d = p.dst[e];
    int key = s * N_ + d;
    unsigned slot = hashN(key);
    while (p.hkN[slot] != key) slot = (slot + 1) & (HTN_ - 1);
    if (p.hvN[slot] != e) return;
    int pos = atomicAdd(&p.cntN[s], 1) & (CAP_ - 1);
    p.listN[s * CAP_ + pos] = (d << 12) | e;
  } else {
    int l = idx - E_;
    int j = p.lgs[l], c = p.lgd[l];
    int key = j * E_ + c;
    unsigned slot = hashE(key);
    while (p.hkE[slot] != key) slot = (slot + 1) & (HTE_ - 1);
    if (p.hvE[slot] != l) return;
    int pos = atomicAdd(&p.cntE[j], 1) & (CAP_ - 1);
    p.listE[j * CAP_ + pos] = c;
  }
}

// ---------------------------------------------------------------------------
// k5: atomic-free gather. Node items: (s, f4) x 32; edge items: (j, f4) x 16.
// Plain coalesced stores; nagg/eagg fully overwritten (no pre-zero needed).
// Grid 384 x 256 = N*32 + E*16 lanes.
// ---------------------------------------------------------------------------
__global__ __launch_bounds__(256) void k5_gather(P p) {
  int idx = blockIdx.x * 256 + threadIdx.x;
  if (idx < N_ * 32) {
    int s = idx >> 5, f4 = idx & 31;
    int deg = min(p.cntN[s], CAP_);
    float4 acc[H_];
#pragma unroll
    for (int h = 0; h < H_; ++h) acc[h] = make_float4(0.f, 0.f, 0.f, 0.f);
    for (int i = 0; i < deg; ++i) {
      int pk = p.listN[s * CAP_ + i];
      int e = pk & (E_ - 1), d = pk >> 12;
#pragma unroll
      for (int h = 0; h < H_; ++h) {
        float a = p.esa[h * E_ + e];
        float4 v = ((const float4*)(p.NV + h * (N_ * FN_) + d * FN_))[f4];
        acc[h].x += a * v.x; acc[h].y += a * v.y;
        acc[h].z += a * v.z; acc[h].w += a * v.w;
      }
    }
#pragma unroll
    for (int h = 0; h < H_; ++h)
      ((float4*)(p.nagg + h * (N_ * FN_) + s * FN_))[f4] = acc[h];
  } else {
    idx -= N_ * 32;
    int j = idx >> 4, f4 = idx & 15;
    int deg = min(p.cntE[j], CAP_);
    float4 acc[H_];
#pragma unroll
    for (int h = 0; h < H_; ++h) acc[h] = make_float4(0.f, 0.f, 0.f, 0.f);
    for (int i = 0; i < deg; ++i) {
      int c = p.listE[j * CAP_ + i];
#pragma unroll
      for (int h = 0; h < H_; ++h) {
        float4 v = ((const float4*)(p.EV + h * (E_ * FE_) + c * FE_))[f4];
        acc[h].x += v.x; acc[h].y += v.y; acc[h].z += v.z; acc[h].w += v.w;
      }
    }
    int cn = p.dst[j];
#pragma unroll
    for (int h = 0; h < H_; ++h) {
      float a = p.nsa[h * N_ + cn];
      ((float4*)(p.eagg + h * (E_ * FE_) + j * FE_))[f4] =
          make_float4(a * acc[h].x, a * acc[h].y, a * acc[h].z, a * acc[h].w);
    }
  }
}

// ---------------------------------------------------------------------------
// k4: output linears + ReLU into d_out. Grid 384 x 256.
// ---------------------------------------------------------------------------
__global__ __launch_bounds__(256) void k4_out(P p) {
  __shared__ float smem[4096];
  const int t = threadIdx.x, bid = blockIdx.x;
  if (bid < 128)
    gemm_tile<128, true>(p.nagg, p.ncW, p.ncb, p.out, 128, (bid >> 1) * 64, (bid & 1) * 64, smem, t);
  else {
    int T2 = bid - 128;
    gemm_tile<64, true>(p.eagg, p.ecW, p.ecb, p.out + (size_t)H_ * N_ * 128, 64, T2 * 64, 0, smem, t);
  }
}

// ---------------------------------------------------------------------------
extern "C" void kernel_launch(void* const* d_in, const int* in_sizes, int n_in,
                              void* d_out, int out_size, void* d_ws, size_t ws_size,
                              hipStream_t stream) {
  P p;
  p.Xn  = (const float*)d_in[0];
  p.Xe  = (const float*)d_in[1];
  p.src = (const int*)d_in[2];
  p.dst = (const int*)d_in[3];
  p.lgs = (const int*)d_in[4];
  p.lgd = (const int*)d_in[5];
  p.nqW = (const float*)d_in[6];  p.nqb = (const float*)d_in[7];
  p.nkW = (const float*)d_in[8];  p.nkb = (const float*)d_in[9];
  p.nvW = (const float*)d_in[10]; p.nvb = (const float*)d_in[11];
  p.eqW = (const float*)d_in[12]; p.eqb = (const float*)d_in[13];
  p.ekW = (const float*)d_in[14]; p.ekb = (const float*)d_in[15];
  p.evW = (const float*)d_in[16]; p.evb = (const float*)d_in[17];
  p.ncW = (const float*)d_in[18]; p.ncb = (const float*)d_in[19];
  p.ecW = (const float*)d_in[20]; p.ecb = (const float*)d_in[21];
  p.out = (float*)d_out;

  float* f = (float*)d_ws;
  p.NV   = f; f += N_ * H_ * FN_;   // 524288
  p.EV   = f; f += E_ * H_ * FE_;   // 1048576
  p.NK   = f; f += N_ * H_;         // 4096
  p.EK   = f; f += E_ * H_;         // 16384
  p.nsa  = f; f += H_ * N_;         // 4096
  p.esa  = f; f += H_ * E_;         // 16384
  p.nagg = f; f += H_ * N_ * FN_;   // 524288
  p.eagg = f; f += H_ * E_ * FE_;   // 1048576
  p.hkN  = (int*)f; f += HTN_;      // hash region contiguous (init -1 in k1)
  p.hvN  = (int*)f; f += HTN_;
  p.hkE  = (int*)f; f += HTE_;
  p.hvE  = (int*)f; f += HTE_;
  p.cntN = (int*)f; f += N_;        // counters (zeroed in k1)
  p.cntE = (int*)f; f += E_;
  p.listN = (int*)f; f += N_ * CAP_;
  p.listE = (int*)f; f += E_ * CAP_;

  k1_prep<<<448, 256, 0, stream>>>(p);
  k2_attn<<<28, 1024, 0, stream>>>(p);
  k3_build<<<80, 256, 0, stream>>>(p);
  k5_gather<<<384, 256, 0, stream>>>(p);
  k4_out<<<384, 256, 0, stream>>>(p);
}